// Round 8
// baseline (170.673 us; speedup 1.0000x reference)
//
#include <hip/hip_runtime.h>
#include <hip/hip_bf16.h>

// F2VConv3d: per-face double-GEMM (both on MFMA) then lightweight vertex gather.
//   W[f,:] = fc[f,:] @ sw          (MFMA1, K=16 padded to 32, computed as W^T)
//   feat[f,cm] = inp[f,cm>>1] * W[f,cm]   (fused epilogue, cvt_pk bf16)
//   g[f] = feat[f,:] @ dw          (MFMA2)
//   out[v] = BN(relu(mean_{f in N(v)} g[f] + bias))
// R7: einsum moved from VALU (819M scalar FMA) to MFMA1; inp staged bf16 in
// LDS; LDS 51.2KB -> 3 blocks/CU; launch_bounds(256,3) caps VGPR at 170.

constexpr int C_IN  = 128;
constexpr int KF    = 16;
constexpr int CM    = 256;    // C_IN * MULT
constexpr int C_OUT = 128;
constexpr int CAP   = 32;     // max tracked faces per vertex
constexpr int GB    = 512;    // k_gather grid (must match k_red width)
constexpr int FT    = 64;     // faces per k_faceg tile
constexpr int FP    = 264;    // feat pitch (u16): 528B rows
constexpr int IPP   = 136;    // inp-bf16 pitch (u16): 272B rows
constexpr int OPW   = 132;    // out staging pitch (f32 words): 528B
constexpr float BN_EPS = 1e-3f;

typedef __attribute__((ext_vector_type(8))) short short8;
typedef __attribute__((ext_vector_type(4))) float f32x4;

__device__ __forceinline__ ushort f2bf(float x) {
  union { float f; unsigned u; } v; v.f = x;
  return (ushort)((v.u + 0x7fffu + ((v.u >> 16) & 1u)) >> 16);
}
__device__ __forceinline__ float b2f(ushort u) {
  return __uint_as_float((unsigned)u << 16);
}
// packed RNE f32x2 -> bf16x2 (v_cvt_pk_bf16_f32); low 16 bits = a
__device__ __forceinline__ uint pk2(float a, float b) {
  __hip_bfloat162 h = __float22bfloat162_rn(float2{a, b});
  return *(uint*)&h;
}

// dwt[n][k] = bf16(dw[k][n]) (MFMA2 B-frag order);
// swt[cm][k] = bf16(sw[k][cm]) padded K 16->32 (MFMA1 A-frag order).
__global__ __launch_bounds__(256) void k_prep(const float* __restrict__ dw,
                                              const float* __restrict__ sw,
                                              ushort* __restrict__ dwt,
                                              ushort* __restrict__ swt) {
  const int b = blockIdx.x, tid = threadIdx.x;
  if (b < 64) {                       // dwt: 128*256 elems, 2/thread
    int i = b * 512 + tid;
#pragma unroll
    for (int r = 0; r < 2; ++r, i += 256) {
      int n = i >> 8, k = i & 255;
      dwt[i] = f2bf(dw[k * C_OUT + n]);
    }
  } else {                            // swt: 256*32 elems, 1/thread
    int i = (b - 64) * 256 + tid;
    int cm = i >> 5, k = i & 31;
    swt[i] = (k < KF) ? f2bf(sw[k * CM + cm]) : (ushort)0;
  }
}

__global__ __launch_bounds__(256) void k_fill(
    const int* __restrict__ face, const int* __restrict__ vt_map,
    int* __restrict__ cnt, int* __restrict__ slots, int n_inc) {
  int i = blockIdx.x * blockDim.x + threadIdx.x;
  if (i < n_inc) {
    int f = i / 3;
    int v = vt_map[face[i]];
    int p = atomicAdd(&cnt[v], 1);
    if (p < CAP) slots[(size_t)v * CAP + p] = f;
  }
}

// 64-face tile, 4 waves. MFMA1: W^T[cm][face] = swt @ fc^T (16 MFMA/wave,
// fc frags built in-register, kg>=2 lanes zero for K-pad). Fused epilogue:
// feat = inp * W via s_inpb (bf16) + cvt_pk, one b64 LDS write per tile.
// MFMA2: 64 MFMA/wave as before. Staging/epilogue unchanged from R6.
__global__ __launch_bounds__(256, 3) void k_faceg(
    const float* __restrict__ inp, const float* __restrict__ fc,
    const ushort* __restrict__ swt, const ushort* __restrict__ dwt,
    ushort* __restrict__ g, int ntiles) {
  __shared__ ushort s_inpb[FT * IPP];   // 17408 B  [face][c] bf16
  __shared__ ushort s_buf[FT * FP];     // 33792 B  feat bf16, aliased staging
  float* s_outf = (float*)s_buf;

  const int tid  = threadIdx.x;
  const int w    = tid >> 6;        // wave -> cm range [w*64, w*64+64)
  const int lane = tid & 63;
  const int rm   = lane & 15;
  const int kg   = lane >> 4;

  // persistent MFMA1 A-frags: swt rows cm = w*64 + ct*16 + rm (16 VGPR)
  short8 a1[4];
#pragma unroll
  for (int ct = 0; ct < 4; ++ct)
    a1[ct] = *(const short8*)&swt[(size_t)(w * 64 + ct * 16 + rm) * 32 + kg * 8];

  const int irow = tid >> 2;          // inp staging: row, 32 consecutive c
  const int ic0  = (tid & 3) * 32;

  for (int tile = blockIdx.x; tile < ntiles; tile += gridDim.x) {
    const int fb = tile * FT;

    // issue inp tile loads (32 floats/thread, coalesced rows)
    float4 xv[8];
    const float* ib = &inp[(size_t)(fb + irow) * C_IN + ic0];
#pragma unroll
    for (int i = 0; i < 8; ++i) xv[i] = *(const float4*)&ib[i * 4];

    // build MFMA1 B-frags from fc (f32 global -> bf16 regs); kg>=2 -> zeros
    short8 b1[4];
#pragma unroll
    for (int ft = 0; ft < 4; ++ft) {
      const float* fr = &fc[(size_t)(fb + ft * 16 + rm) * KF + (kg & 1) * 8];
      const float4 p0 = *(const float4*)fr;
      const float4 p1 = *(const float4*)(fr + 4);
      uint4 u;
      u.x = pk2(p0.x, p0.y); u.y = pk2(p0.z, p0.w);
      u.z = pk2(p1.x, p1.y); u.w = pk2(p1.z, p1.w);
      if (kg >= 2) u = uint4{0, 0, 0, 0};
      b1[ft] = *(short8*)&u;
    }
    __syncthreads();                  // A: prev tile fully drained

    // stage inp -> bf16 LDS (4x b128 writes)
#pragma unroll
    for (int i = 0; i < 4; ++i) {
      uint4 u;
      u.x = pk2(xv[2 * i].x,     xv[2 * i].y);
      u.y = pk2(xv[2 * i].z,     xv[2 * i].w);
      u.z = pk2(xv[2 * i + 1].x, xv[2 * i + 1].y);
      u.w = pk2(xv[2 * i + 1].z, xv[2 * i + 1].w);
      *(uint4*)&s_inpb[irow * IPP + ic0 + i * 8] = u;
    }
    __syncthreads();                  // B: s_inpb ready, s_buf free

    // MFMA1 + fused inp-multiply epilogue -> feat bf16 in s_buf
    // D layout: col = lane&15 = face_local, row = kg*4+r = cm_local (m89)
#pragma unroll
    for (int ft = 0; ft < 4; ++ft) {
#pragma unroll
      for (int ct = 0; ct < 4; ++ct) {
        f32x4 acc = {0.f, 0.f, 0.f, 0.f};
        acc = __builtin_amdgcn_mfma_f32_16x16x32_bf16(a1[ct], b1[ft], acc, 0, 0, 0);
        const int face = ft * 16 + rm;
        const int cmb  = w * 64 + ct * 16 + kg * 4;   // multiple of 4
        const float i0 = b2f(s_inpb[face * IPP + (cmb >> 1)]);
        const float i1 = b2f(s_inpb[face * IPP + (cmb >> 1) + 1]);
        uint2 pw;
        pw.x = pk2(acc[0] * i0, acc[1] * i0);
        pw.y = pk2(acc[2] * i1, acc[3] * i1);
        *(uint2*)&s_buf[face * FP + cmb] = pw;
      }
    }

    // MFMA2 B-frags (dwt, L2-hot), short live range
    short8 bfr[2][8];
#pragma unroll
    for (int nt = 0; nt < 2; ++nt) {
      const int n = (w * 2 + nt) * 16 + rm;
#pragma unroll
      for (int ks = 0; ks < 8; ++ks)
        bfr[nt][ks] = *(const short8*)&dwt[n * 256 + ks * 32 + kg * 8];
    }
    __syncthreads();                  // C: feat ready

    f32x4 acc2[4][2];
#pragma unroll
    for (int fs = 0; fs < 4; ++fs)
#pragma unroll
      for (int nt = 0; nt < 2; ++nt)
        acc2[fs][nt] = (f32x4){0.f, 0.f, 0.f, 0.f};

#pragma unroll
    for (int fs = 0; fs < 4; ++fs)
#pragma unroll
      for (int ks = 0; ks < 8; ++ks) {
        const short8 af = *(const short8*)&s_buf[(fs * 16 + rm) * FP + ks * 32 + kg * 8];
        acc2[fs][0] = __builtin_amdgcn_mfma_f32_16x16x32_bf16(af, bfr[0][ks], acc2[fs][0], 0, 0, 0);
        acc2[fs][1] = __builtin_amdgcn_mfma_f32_16x16x32_bf16(af, bfr[1][ks], acc2[fs][1], 0, 0, 0);
      }
    __syncthreads();                  // D: all feat reads done (alias!)

    // f32 staging, XOR-swizzled cols
#pragma unroll
    for (int fs = 0; fs < 4; ++fs)
#pragma unroll
      for (int nt = 0; nt < 2; ++nt)
#pragma unroll
        for (int r = 0; r < 4; ++r) {
          const int row = fs * 16 + kg * 4 + r;
          const int col = (w * 2 + nt) * 16 + rm;
          s_outf[row * OPW + (col ^ ((row & 7) << 2))] = acc2[fs][nt][r];
        }
    __syncthreads();                  // E: staging ready

    // packed bf16 g stores: thread -> 1/4 row (32 channels)
    const int cb = (tid & 3) * 32;
    const int sz = (irow & 7) << 2;
#pragma unroll
    for (int i = 0; i < 4; ++i) {
      const float4 a = *(const float4*)&s_outf[irow * OPW + ((cb + 8 * i) ^ sz)];
      const float4 b = *(const float4*)&s_outf[irow * OPW + ((cb + 8 * i + 4) ^ sz)];
      short8 pk;
      uint4 u;
      u.x = pk2(a.x, a.y); u.y = pk2(a.z, a.w);
      u.z = pk2(b.x, b.y); u.w = pk2(b.z, b.w);
      pk = *(short8*)&u;
      *(short8*)&g[(size_t)(fb + irow) * C_OUT + cb + 8 * i] = pk;
    }
  }
}

// 16 verts/tile, 16 threads/vert. Partials written TRANSPOSED: part[col][GB].
__global__ __launch_bounds__(256) void k_gather(
    const ushort* __restrict__ g, const int* __restrict__ cnt,
    const int* __restrict__ slots, const int* __restrict__ nf_cnt,
    const float* __restrict__ bias, float* __restrict__ out,
    float* __restrict__ part, int nv, int ntiles) {
  __shared__ int   s_slots[16][CAP];
  __shared__ int   s_deg[16];
  __shared__ float s_red[256][8];

  const int tid = threadIdx.x;
  const int q   = tid & 15;
  const int vg  = tid >> 4;
  const int c8  = q * 8;

  float bs[8];
#pragma unroll
  for (int j = 0; j < 8; ++j) bs[j] = bias[c8 + j];
  float st_s[8], st_q[8];
#pragma unroll
  for (int j = 0; j < 8; ++j) { st_s[j] = 0.f; st_q[j] = 0.f; }

  for (int tile = blockIdx.x; tile < ntiles; tile += gridDim.x) {
    const int vbase = tile * 16;
    __syncthreads();
    for (int i = tid; i < 16 * CAP; i += 256)
      s_slots[i >> 5][i & 31] = slots[((size_t)vbase << 5) + i];
    if (tid < 16) {
      int d = cnt[vbase + tid];
      s_deg[tid] = d > CAP ? CAP : d;
    }
    __syncthreads();

    const int v = vbase + vg;
    float a[8];
#pragma unroll
    for (int j = 0; j < 8; ++j) a[j] = 0.f;
    const int deg = s_deg[vg];
    int t = 0;
    for (; t + 2 <= deg; t += 2) {
      const int f0 = s_slots[vg][t], f1 = s_slots[vg][t + 1];
      const short8 r0 = *(const short8*)&g[(size_t)f0 * C_OUT + c8];
      const short8 r1 = *(const short8*)&g[(size_t)f1 * C_OUT + c8];
#pragma unroll
      for (int j = 0; j < 8; ++j)
        a[j] += b2f((ushort)r0[j]) + b2f((ushort)r1[j]);
    }
    if (t < deg) {
      const short8 r0 = *(const short8*)&g[(size_t)s_slots[vg][t] * C_OUT + c8];
#pragma unroll
      for (int j = 0; j < 8; ++j) a[j] += b2f((ushort)r0[j]);
    }

    int d = nf_cnt[v]; if (d < 1) d = 1;
    const float inv = 1.0f / (float)d;
    float r[8];
#pragma unroll
    for (int j = 0; j < 8; ++j) {
      r[j] = fmaxf(fmaf(a[j], inv, bs[j]), 0.f);
      st_s[j] += r[j];
      st_q[j] = fmaf(r[j], r[j], st_q[j]);
    }
    *(float4*)&out[(size_t)v * C_OUT + c8]     = make_float4(r[0], r[1], r[2], r[3]);
    *(float4*)&out[(size_t)v * C_OUT + c8 + 4] = make_float4(r[4], r[5], r[6], r[7]);
  }

  __syncthreads();
#pragma unroll
  for (int j = 0; j < 8; ++j) s_red[tid][j] = st_s[j];
  __syncthreads();
  if (tid < 16) {
    for (int j = 0; j < 8; ++j) {
      float x = 0.f;
      for (int gg = 0; gg < 16; ++gg) x += s_red[gg * 16 + tid][j];
      part[(size_t)(tid * 8 + j) * GB + blockIdx.x] = x;           // transposed
    }
  }
  __syncthreads();
#pragma unroll
  for (int j = 0; j < 8; ++j) s_red[tid][j] = st_q[j];
  __syncthreads();
  if (tid < 16) {
    for (int j = 0; j < 8; ++j) {
      float x = 0.f;
      for (int gg = 0; gg < 16; ++gg) x += s_red[gg * 16 + tid][j];
      part[(size_t)(128 + tid * 8 + j) * GB + blockIdx.x] = x;     // transposed
    }
  }
}

// 256 blocks: block j reduces part[j][0:GB] (coalesced) -> red[j].
__global__ __launch_bounds__(256) void k_red(const float* __restrict__ part,
                                             float* __restrict__ red) {
  const int j   = blockIdx.x;
  const int tid = threadIdx.x;
  float v = part[(size_t)j * GB + tid] + part[(size_t)j * GB + 256 + tid];
#pragma unroll
  for (int off = 32; off > 0; off >>= 1) v += __shfl_down(v, off);
  __shared__ float sred[4];
  if ((tid & 63) == 0) sred[tid >> 6] = v;
  __syncthreads();
  if (tid == 0) red[j] = sred[0] + sred[1] + sred[2] + sred[3];
}

__global__ void k_fin(const float* __restrict__ red,
                      const float* __restrict__ gamma, const float* __restrict__ beta,
                      float* __restrict__ scale, float* __restrict__ shift, float invN) {
  int o = threadIdx.x;   // 128
  float mean = red[o] * invN;
  float var  = red[128 + o] * invN - mean * mean;
  float sc   = gamma[o] * rsqrtf(var + BN_EPS);
  scale[o] = sc;
  shift[o] = fmaf(-mean, sc, beta[o]);
}

__global__ __launch_bounds__(256) void k_bn(float* __restrict__ out,
                                            const float* __restrict__ scale,
                                            const float* __restrict__ shift, int n4) {
  int idx = blockIdx.x * blockDim.x + threadIdx.x;
  int stride = gridDim.x * blockDim.x;
  for (; idx < n4; idx += stride) {
    float4 v = ((const float4*)out)[idx];
    int base = (idx * 4) & (C_OUT - 1);
    float4 sc = *(const float4*)&scale[base];
    float4 sh = *(const float4*)&shift[base];
    v.x = fmaf(v.x, sc.x, sh.x);
    v.y = fmaf(v.y, sc.y, sh.y);
    v.z = fmaf(v.z, sc.z, sh.z);
    v.w = fmaf(v.w, sc.w, sh.w);
    ((float4*)out)[idx] = v;
  }
}

extern "C" void kernel_launch(void* const* d_in, const int* in_sizes, int n_in,
                              void* d_out, int out_size, void* d_ws, size_t ws_size,
                              hipStream_t stream) {
  const float* inputs = (const float*)d_in[0];
  const float* fc     = (const float*)d_in[1];
  const int*   face   = (const int*)d_in[2];
  const int*   nf_cnt = (const int*)d_in[3];
  const int*   vt_map = (const int*)d_in[4];
  const float* sw     = (const float*)d_in[5];
  const float* dw     = (const float*)d_in[6];
  const float* bias   = (const float*)d_in[7];
  const float* gamma  = (const float*)d_in[8];
  const float* beta   = (const float*)d_in[9];
  float* out = (float*)d_out;

  const int nf = in_sizes[0] / C_IN;   // 200000
  const int nv = in_sizes[3];          // 100000

  // ws: cnt[nv] | scale[128] | shift[128] | red[256] | part[256*GB]
  //     | dwt[128*256 u16] | swt[256*32 u16] | slots[nv*CAP] | g[nf*128 u16]
  char* p = (char*)d_ws;
  int*    cnt   = (int*)p;            p += (size_t)nv * 4;
  float*  scale = (float*)p;          p += C_OUT * 4;
  float*  shift = (float*)p;          p += C_OUT * 4;
  float*  red   = (float*)p;          p += 256 * 4;
  float*  part  = (float*)p;          p += (size_t)256 * GB * 4;
  ushort* dwt   = (ushort*)p;         p += (size_t)C_OUT * CM * 2;
  ushort* swt   = (ushort*)p;         p += (size_t)CM * 32 * 2;
  int*    slots = (int*)p;            p += (size_t)nv * CAP * 4;
  ushort* g     = (ushort*)p;

  hipMemsetAsync(cnt, 0, (size_t)nv * 4, stream);

  k_prep<<<96, 256, 0, stream>>>(dw, sw, dwt, swt);

  const int n_inc = nf * 3;
  k_fill<<<(n_inc + 255) / 256, 256, 0, stream>>>(face, vt_map, cnt, slots, n_inc);

  const int ntiles_f = (nf + FT - 1) / FT;   // 3125
  k_faceg<<<1024, 256, 0, stream>>>(inputs, fc, swt, dwt, g, ntiles_f);

  const int ntiles_v = (nv + 15) / 16;       // 6250
  k_gather<<<GB, 256, 0, stream>>>(g, cnt, slots, nf_cnt, bias, out, part, nv, ntiles_v);

  k_red<<<256, 256, 0, stream>>>(part, red);
  k_fin<<<1, 128, 0, stream>>>(red, gamma, beta, scale, shift, 1.0f / (float)nv);

  const int n4 = (nv * C_OUT) / 4;
  k_bn<<<4096, 256, 0, stream>>>(out, scale, shift, n4);
}